// Round 5
// baseline (24.466 us; speedup 1.0000x reference)
//
#include <hip/hip_runtime.h>
#include <math.h>

#define NB 16
#define KB 32
#define KA 16
#define G  128
#define GP1 (G + 1)

// ws layout (floats):
//   [0]=xlo  [1]=ginv (=G/(xhi-xlo))  [2]=xhi  [3..63] pad
//   [64 ..)  float2 lut[NB][GP1] : {c0,c1} per x-cell; F_b(x) = c0 + c1*x
//            (row stride GP1=129 spreads bucket rows across LDS bank pairs;
//             entry G duplicates entry G-1 so index G is safe)
#define LUT_F2   (NB * GP1)
#define WS_FLOATS (64 + 2 * LUT_F2)

__device__ __forceinline__ float softplus_f(float v) {
    return fmaxf(v, 0.0f) + log1pf(expf(-fabsf(v)));
}

// ---------------- kernel 1: single block builds the x-domain PWL table ----------------
__global__ __launch_bounds__(256) void build_lut_kernel(
    const float* __restrict__ x_mins,
    const float* __restrict__ x_maxs,
    const float* __restrict__ clip_los,
    const float* __restrict__ clip_his,
    const float* __restrict__ base_knots,
    const float* __restrict__ base_raw_w,
    const float* __restrict__ base_bias,
    const float* __restrict__ adj_knots,
    const float* __restrict__ adj_raw_w,
    const float* __restrict__ adj_bias,
    float* __restrict__ ws)
{
    __shared__ float  s_bw[KB];
    __shared__ float  s_aw[NB][KA];
    __shared__ float  s_bias[NB];
    __shared__ float4 s_abc[NB];          // {a, c, Lb, Hb}
    __shared__ float  s_xlo_b[NB], s_xhi_b[NB];
    __shared__ float  s_xr[2];
    __shared__ float  s_f[NB][GP1];

    const int tid = threadIdx.x;

    if (tid < KB) s_bw[tid] = softplus_f(base_raw_w[tid]);
    if (tid < NB * KA) s_aw[tid >> 4][tid & (KA - 1)] = softplus_f(adj_raw_w[tid]);
    if (tid < NB) {
        const float mn = x_mins[tid], mx = x_maxs[tid];
        const float inva = mx - mn + 1e-12f;
        const float a = 1.0f / inva;
        const float c = -mn * a;
        const float lo = clip_los[tid], hi = clip_his[tid];
        // fold clip bounds through monotone affine + [0,1] clamp;
        // non-finite bound => no clipping on that side (max/min vs ∓inf are identity)
        const float Lb = isfinite(lo) ? fminf(fmaxf(fmaf(lo, a, c), 0.0f), 1.0f) : 0.0f;
        const float Hb = isfinite(hi) ? fmaxf(fminf(fmaf(hi, a, c), 1.0f), 0.0f) : 1.0f;
        s_abc[tid] = make_float4(a, c, Lb, Hb);
        s_bias[tid] = adj_bias[tid] + base_bias[0];
        // active x-range of this bucket (F_b is constant outside it)
        const float x0 = fmaf(Lb, inva, mn);
        const float x1 = fmaf(Hb, inva, mn);
        s_xlo_b[tid] = fminf(x0, x1);
        s_xhi_b[tid] = fmaxf(x0, x1);
    }
    __syncthreads();

    if (tid == 0) {
        float xlo = s_xlo_b[0], xhi = s_xhi_b[0];
        for (int b = 1; b < NB; ++b) {
            xlo = fminf(xlo, s_xlo_b[b]);
            xhi = fmaxf(xhi, s_xhi_b[b]);
        }
        if (!(xhi > xlo)) xhi = xlo + 1.0f;   // degenerate guard
        s_xr[0] = xlo; s_xr[1] = xhi;
        ws[0] = xlo;
        ws[1] = (float)G / (xhi - xlo);
        ws[2] = xhi;
    }
    __syncthreads();

    const float xlo = s_xr[0], xhi = s_xr[1];
    const float hstep = (xhi - xlo) * (1.0f / (float)G);

    // exact F_b at the NB x GP1 gridpoints
    for (int gp = tid; gp < NB * GP1; gp += 256) {
        const int b = gp / GP1, j = gp - b * GP1;
        const float xj = fmaf(hstep, (float)j, xlo);
        const float4 p = s_abc[b];
        const float v = fminf(fmaxf(fmaf(xj, p.x, p.y), p.z), p.w);
        float f = s_bias[b];
        #pragma unroll 8
        for (int k = 0; k < KB; ++k)
            f = fmaf(s_bw[k], fminf(v, base_knots[k]), f);
        #pragma unroll 8
        for (int k = 0; k < KA; ++k)
            f = fmaf(s_aw[b][k], fminf(v, adj_knots[k]), f);
        s_f[b][j] = f;
    }
    __syncthreads();

    float2* lut = (float2*)(ws + 64);
    const float hinv = 1.0f / hstep;
    for (int e = tid; e < NB * GP1; e += 256) {
        const int b = e / GP1, j = e - b * GP1;
        const int jc = min(j, G - 1);        // entry G duplicates last cell
        const float fl = s_f[b][jc], fr = s_f[b][jc + 1];
        const float c1 = (fr - fl) * hinv;
        const float xj = fmaf(hstep, (float)jc, xlo);
        const float c0 = fmaf(-c1, xj, fl);
        lut[e] = make_float2(c0, c1);
    }
}

// ---------------- kernel 2: streaming evaluation, 8 elements/thread ----------------
__global__ __launch_bounds__(256) void BucketAdjustedHinge_kernel(
    const float* __restrict__ x,
    const int*   __restrict__ bucket_idx,
    const float* __restrict__ ws,
    float*       __restrict__ out,
    int n)
{
    __shared__ float2 s_lut[LUT_F2];

    const int tid = threadIdx.x;
    const int gsz = gridDim.x * blockDim.x;
    const int t   = blockIdx.x * blockDim.x + tid;
    const int n4  = n >> 2;

    const float4* __restrict__ x4v = (const float4*)x;
    const int4*   __restrict__ b4v = (const int4*)bucket_idx;
    float4*       __restrict__ o4v = (float4*)out;

    // issue main-stream loads BEFORE the LDS copy/barrier so HBM latency hides
    float4 xa, xb; int4 ba, bb;
    const bool va = t < n4, vb = (t + gsz) < n4;
    if (va) { xa = x4v[t];        ba = b4v[t]; }
    if (vb) { xb = x4v[t + gsz];  bb = b4v[t + gsz]; }
    const float xlo  = ws[0];
    const float ginv = ws[1];
    const float xhi  = ws[2];

    // stage LUT (16.5 KB) from L2 into LDS
    {
        const float4* __restrict__ src = (const float4*)(ws + 64);
        float4* __restrict__ dst = (float4*)s_lut;
        for (int i = tid; i < LUT_F2 / 2; i += 256) dst[i] = src[i];
    }
    __syncthreads();

    #define EVAL1(xr, b, dst)                                              \
        {                                                                  \
            const float xc = fminf(fmaxf((xr), xlo), xhi);                 \
            const float tt = (xc - xlo) * ginv;                            \
            const int cell = min((int)tt, G - 1);                          \
            const float2 cf = s_lut[(b) * GP1 + cell];                     \
            (dst) = fmaf(xc, cf.y, cf.x);                                  \
        }

    if (va) {
        float4 r;
        EVAL1(xa.x, ba.x, r.x); EVAL1(xa.y, ba.y, r.y);
        EVAL1(xa.z, ba.z, r.z); EVAL1(xa.w, ba.w, r.w);
        o4v[t] = r;
    }
    if (vb) {
        float4 r;
        EVAL1(xb.x, bb.x, r.x); EVAL1(xb.y, bb.y, r.y);
        EVAL1(xb.z, bb.z, r.z); EVAL1(xb.w, bb.w, r.w);
        o4v[t + gsz] = r;
    }

    // generic tails (unused at N=4M with 2048x256 grid, kept for safety)
    for (int i = t + 2 * gsz; i < n4; i += gsz) {
        const float4 xv = x4v[i];
        const int4   bv = b4v[i];
        float4 r;
        EVAL1(xv.x, bv.x, r.x); EVAL1(xv.y, bv.y, r.y);
        EVAL1(xv.z, bv.z, r.z); EVAL1(xv.w, bv.w, r.w);
        o4v[i] = r;
    }
    const int rem_start = n4 << 2;
    for (int i = rem_start + t; i < n; i += gsz) {
        float r;
        EVAL1(x[i], bucket_idx[i], r);
        out[i] = r;
    }
    #undef EVAL1
}

extern "C" void kernel_launch(void* const* d_in, const int* in_sizes, int n_in,
                              void* d_out, int out_size, void* d_ws, size_t ws_size,
                              hipStream_t stream) {
    const float* x          = (const float*)d_in[0];
    const float* x_mins     = (const float*)d_in[1];
    const float* x_maxs     = (const float*)d_in[2];
    const float* clip_los   = (const float*)d_in[3];
    const float* clip_his   = (const float*)d_in[4];
    const float* base_knots = (const float*)d_in[5];
    const float* base_raw_w = (const float*)d_in[6];
    const float* base_bias  = (const float*)d_in[7];
    const float* adj_knots  = (const float*)d_in[8];
    const float* adj_raw_w  = (const float*)d_in[9];
    const float* adj_bias   = (const float*)d_in[10];
    const int*   bucket_idx = (const int*)d_in[11];
    float* out = (float*)d_out;
    float* ws  = (float*)d_ws;

    const int n = in_sizes[0];

    build_lut_kernel<<<1, 256, 0, stream>>>(
        x_mins, x_maxs, clip_los, clip_his,
        base_knots, base_raw_w, base_bias,
        adj_knots, adj_raw_w, adj_bias, ws);

    const int blocks = 2048;   // 8 wg/CU; each thread handles 8 elements
    BucketAdjustedHinge_kernel<<<blocks, 256, 0, stream>>>(
        x, bucket_idx, ws, out, n);
}

// Round 6
// 18.105 us; speedup vs baseline: 1.3513x; 1.3513x over previous
//
#include <hip/hip_runtime.h>
#include <math.h>

#define NB 16
#define KB 32
#define KA 16
#define G  128
#define GP1 (G + 1)
#define LUT_E (NB * GP1)          // 2064 float2 entries
#define ITERS 4

// ws layout (floats):
//   [0]=xlo  [1]=ginv=G/(xhi-xlo)  [2]=xhi  [3]=xlo*ginv  [4..63] pad
//   [64 ..]  float2 lut[NB][GP1]: {c0,c1}; F_b(x) = c0 + c1*x on cell;
//            entry G duplicates entry G-1 so cell index is always valid.

__device__ __forceinline__ float softplus_f(float v) {
    return fmaxf(v, 0.0f) + log1pf(expf(-fabsf(v)));
}

// ---------------- kernel 1: 16 blocks, one bucket per block ----------------
__global__ __launch_bounds__(256) void build_lut_kernel(
    const float* __restrict__ x_mins,
    const float* __restrict__ x_maxs,
    const float* __restrict__ clip_los,
    const float* __restrict__ clip_his,
    const float* __restrict__ base_knots,
    const float* __restrict__ base_raw_w,
    const float* __restrict__ base_bias,
    const float* __restrict__ adj_knots,
    const float* __restrict__ adj_raw_w,
    const float* __restrict__ adj_bias,
    float* __restrict__ ws)
{
    __shared__ float s_bw[KB], s_bk[KB], s_aw[KA], s_ak[KA];
    __shared__ float s_x0[NB], s_x1[NB];
    __shared__ float s_prm[4];          // {a, c, Lb, Hb} for THIS block's bucket
    __shared__ float s_f[GP1];

    const int tid = threadIdx.x;
    const int b   = blockIdx.x;

    if (tid < KB) { s_bw[tid] = softplus_f(base_raw_w[tid]); s_bk[tid] = base_knots[tid]; }
    if (tid < KA) { s_aw[tid] = softplus_f(adj_raw_w[b * KA + tid]); s_ak[tid] = adj_knots[tid]; }
    if (tid < NB) {
        const float mn = x_mins[tid], mx = x_maxs[tid];
        const float inva = mx - mn + 1e-12f;
        const float a = 1.0f / inva;
        const float c = -mn * a;
        const float lo = clip_los[tid], hi = clip_his[tid];
        // fold clip bounds through monotone affine + [0,1] clamp;
        // non-finite bound => no clipping on that side
        const float Lb = isfinite(lo) ? fminf(fmaxf(fmaf(lo, a, c), 0.0f), 1.0f) : 0.0f;
        const float Hb = isfinite(hi) ? fmaxf(fminf(fmaf(hi, a, c), 1.0f), 0.0f) : 1.0f;
        // active x-range of bucket tid (F is constant outside)
        const float x0 = fmaf(Lb, inva, mn);
        const float x1 = fmaf(Hb, inva, mn);
        s_x0[tid] = fminf(x0, x1);
        s_x1[tid] = fmaxf(x0, x1);
        if (tid == b) { s_prm[0] = a; s_prm[1] = c; s_prm[2] = Lb; s_prm[3] = Hb; }
    }
    __syncthreads();

    float xlo = s_x0[0], xhi = s_x1[0];
    #pragma unroll
    for (int i = 1; i < NB; ++i) { xlo = fminf(xlo, s_x0[i]); xhi = fmaxf(xhi, s_x1[i]); }
    if (!(xhi > xlo)) xhi = xlo + 1.0f;            // degenerate guard
    const float ginv  = (float)G / (xhi - xlo);
    const float hstep = (xhi - xlo) * (1.0f / (float)G);

    if (b == 0 && tid == 0) {
        ws[0] = xlo; ws[1] = ginv; ws[2] = xhi; ws[3] = xlo * ginv;
    }

    if (tid < GP1) {
        const float xj = fmaf(hstep, (float)tid, xlo);
        const float v = fminf(fmaxf(fmaf(xj, s_prm[0], s_prm[1]), s_prm[2]), s_prm[3]);
        float f = adj_bias[b] + base_bias[0];
        #pragma unroll 8
        for (int k = 0; k < KB; ++k)
            f = fmaf(s_bw[k], fminf(v, s_bk[k]), f);
        #pragma unroll 8
        for (int k = 0; k < KA; ++k)
            f = fmaf(s_aw[k], fminf(v, s_ak[k]), f);
        s_f[tid] = f;
    }
    __syncthreads();

    if (tid < GP1) {
        const int jc = min(tid, G - 1);            // entry G duplicates last cell
        const float fl = s_f[jc], fr = s_f[jc + 1];
        const float c1 = (fr - fl) * ginv;
        const float xj = fmaf(hstep, (float)jc, xlo);
        const float c0 = fmaf(-c1, xj, fl);
        ((float2*)(ws + 64))[b * GP1 + tid] = make_float2(c0, c1);
    }
}

// ---------------- kernel 2: streaming eval, 16 elements/thread ----------------
__global__ __launch_bounds__(256) void BucketAdjustedHinge_kernel(
    const float* __restrict__ x,
    const int*   __restrict__ bucket_idx,
    const float* __restrict__ ws,
    float*       __restrict__ out,
    int n)
{
    __shared__ float2 s_lut[LUT_E];

    const int tid = threadIdx.x;
    const int gsz = gridDim.x * blockDim.x;
    const int t   = blockIdx.x * blockDim.x + tid;
    const int n4  = n >> 2;

    const float4* __restrict__ x4v = (const float4*)x;
    const int4*   __restrict__ b4v = (const int4*)bucket_idx;
    float4*       __restrict__ o4v = (float4*)out;

    // issue ALL main-stream loads before staging: HBM latency hides under the
    // LDS-staging loop + barrier (whose vmcnt(0) drain needs ~1 latency anyway)
    float4 xa[ITERS]; int4 ba[ITERS];
    #pragma unroll
    for (int k = 0; k < ITERS; ++k) {
        const int idx = t + k * gsz;
        if (idx < n4) { xa[k] = x4v[idx]; ba[k] = b4v[idx]; }
    }

    const float xlo  = ws[0];
    const float ginv = ws[1];
    const float xhi  = ws[2];
    const float xlg  = ws[3];

    // stage 16.5 KB LUT from L2/L3 into LDS (1032 float4)
    {
        const float4* __restrict__ src = (const float4*)(ws + 64);
        float4* __restrict__ dst = (float4*)s_lut;
        #pragma unroll
        for (int i = 0; i < 5; ++i) {
            const int j = tid + i * 256;
            if (j < LUT_E / 2) dst[j] = src[j];
        }
    }
    __syncthreads();

    #define EVAL1(xr, b, dstf)                                             \
        {                                                                  \
            const float xc = fminf(fmaxf((xr), xlo), xhi);                 \
            const float tt = fmaf(xc, ginv, -xlg);                         \
            const int cell = min((int)tt, G - 1);                          \
            const float2 cf = s_lut[(b) * GP1 + cell];                     \
            (dstf) = fmaf(xc, cf.y, cf.x);                                 \
        }

    #pragma unroll
    for (int k = 0; k < ITERS; ++k) {
        const int idx = t + k * gsz;
        if (idx < n4) {
            float4 r;
            EVAL1(xa[k].x, ba[k].x, r.x); EVAL1(xa[k].y, ba[k].y, r.y);
            EVAL1(xa[k].z, ba[k].z, r.z); EVAL1(xa[k].w, ba[k].w, r.w);
            o4v[idx] = r;
        }
    }

    // safety tails (unused at N=4M with 1024x256xITERS=4 covering n4 exactly)
    for (int idx = t + ITERS * gsz; idx < n4; idx += gsz) {
        const float4 xv = x4v[idx];
        const int4   bv = b4v[idx];
        float4 r;
        EVAL1(xv.x, bv.x, r.x); EVAL1(xv.y, bv.y, r.y);
        EVAL1(xv.z, bv.z, r.z); EVAL1(xv.w, bv.w, r.w);
        o4v[idx] = r;
    }
    for (int i = (n4 << 2) + t; i < n; i += gsz) {
        float r;
        EVAL1(x[i], bucket_idx[i], r);
        out[i] = r;
    }
    #undef EVAL1
}

extern "C" void kernel_launch(void* const* d_in, const int* in_sizes, int n_in,
                              void* d_out, int out_size, void* d_ws, size_t ws_size,
                              hipStream_t stream) {
    const float* x          = (const float*)d_in[0];
    const float* x_mins     = (const float*)d_in[1];
    const float* x_maxs     = (const float*)d_in[2];
    const float* clip_los   = (const float*)d_in[3];
    const float* clip_his   = (const float*)d_in[4];
    const float* base_knots = (const float*)d_in[5];
    const float* base_raw_w = (const float*)d_in[6];
    const float* base_bias  = (const float*)d_in[7];
    const float* adj_knots  = (const float*)d_in[8];
    const float* adj_raw_w  = (const float*)d_in[9];
    const float* adj_bias   = (const float*)d_in[10];
    const int*   bucket_idx = (const int*)d_in[11];
    float* out = (float*)d_out;
    float* ws  = (float*)d_ws;

    const int n = in_sizes[0];

    build_lut_kernel<<<NB, 256, 0, stream>>>(
        x_mins, x_maxs, clip_los, clip_his,
        base_knots, base_raw_w, base_bias,
        adj_knots, adj_raw_w, adj_bias, ws);

    // 1024 blocks = 4 wg/CU; each thread: 4 float4 loads in flight + 4 int4
    const int blocks = 1024;
    BucketAdjustedHinge_kernel<<<blocks, 256, 0, stream>>>(
        x, bucket_idx, ws, out, n);
}